// Round 1
// baseline (1973.734 us; speedup 1.0000x reference)
//
#include <hip/hip_runtime.h>

#define N_ENT   100000
#define N_REL   500
#define DD      50
#define N_EDGES 2000000

// ---------------------------------------------------------------------------
// Small GEMM precompute: Y{a,b,c}[m][j] = sum_k X[m][k] * W{a,b,c}[k][j] (+bd)
// W matrices are 50x50 row-major, staged in LDS. One thread per (m,j).
// ---------------------------------------------------------------------------
__global__ void ent_pre_kernel(const float* __restrict__ X, int M,
                               const float* __restrict__ Wa,
                               const float* __restrict__ Wb,
                               const float* __restrict__ Wc,   // may be null
                               const float* __restrict__ bd,   // may be null
                               float* __restrict__ Ya,
                               float* __restrict__ Yb,
                               float* __restrict__ Yc)
{
    __shared__ float sWa[DD * DD];
    __shared__ float sWb[DD * DD];
    __shared__ float sWc[DD * DD];
    const bool has_c = (Wc != nullptr);
    for (int i = threadIdx.x; i < DD * DD; i += blockDim.x) {
        sWa[i] = Wa[i];
        sWb[i] = Wb[i];
        if (has_c) sWc[i] = Wc[i];
    }
    __syncthreads();
    int idx = blockIdx.x * blockDim.x + threadIdx.x;
    if (idx >= M * DD) return;
    int m = idx / DD, j = idx - m * DD;
    const float* x = X + m * DD;
    float aa = 0.f, ab = 0.f;
    float ac = (has_c && bd) ? bd[j] : 0.f;
    for (int k = 0; k < DD; k++) {
        float xv = x[k];
        aa += xv * sWa[k * DD + j];
        ab += xv * sWb[k * DD + j];
        if (has_c) ac += xv * sWc[k * DD + j];
    }
    Ya[idx] = aa;
    Yb[idx] = ab;
    if (has_c) Yc[idx] = ac;
}

// rel_out = (relu?) Rin @ Wr ; RW_out = Rin @ Wmid     (M = N_REL)
__global__ void rel_pre_kernel(const float* __restrict__ Rin,
                               const float* __restrict__ Wr,
                               const float* __restrict__ Wmid,
                               int do_relu,
                               float* __restrict__ rel_out,
                               float* __restrict__ RW_out)
{
    __shared__ float sWr[DD * DD];
    __shared__ float sWm[DD * DD];
    for (int i = threadIdx.x; i < DD * DD; i += blockDim.x) {
        sWr[i] = Wr[i];
        sWm[i] = Wmid[i];
    }
    __syncthreads();
    int idx = blockIdx.x * blockDim.x + threadIdx.x;
    if (idx >= N_REL * DD) return;
    int m = idx / DD, j = idx - m * DD;
    const float* x = Rin + m * DD;
    float ar = 0.f, am = 0.f;
    for (int k = 0; k < DD; k++) {
        float xv = x[k];
        ar += xv * sWr[k * DD + j];
        am += xv * sWm[k * DD + j];
    }
    if (do_relu) ar = fmaxf(ar, 0.f);
    rel_out[idx] = ar;
    RW_out[idx] = am;
}

// ---------------------------------------------------------------------------
// CSR build: histogram of head index, exclusive scan, scatter sorted triples
// ---------------------------------------------------------------------------
__global__ void hist_kernel(const int* __restrict__ h, int* __restrict__ counts, int nE)
{
    int e = blockIdx.x * blockDim.x + threadIdx.x;
    if (e < nE) atomicAdd(&counts[h[e]], 1);
}

__global__ void scan_kernel(const int* __restrict__ counts,
                            int* __restrict__ offs,
                            int* __restrict__ cursor, int nU)
{
    __shared__ int part[1024];
    int t = threadIdx.x;
    int chunk = (nU + 1023) / 1024;
    int b = t * chunk;
    int e = min(b + chunk, nU);
    int s = 0;
    for (int i = b; i < e; i++) s += counts[i];
    part[t] = s;
    __syncthreads();
    for (int off = 1; off < 1024; off <<= 1) {
        int v = (t >= off) ? part[t - off] : 0;
        __syncthreads();
        part[t] += v;
        __syncthreads();
    }
    int run = part[t] - s;  // exclusive base
    for (int i = b; i < e; i++) {
        offs[i] = run;
        cursor[i] = run;
        run += counts[i];
    }
    if (b < nU && e == nU) offs[nU] = run;
}

__global__ void scatter_kernel(const int* __restrict__ h,
                               const int* __restrict__ r,
                               const int* __restrict__ t,
                               int* __restrict__ cursor,
                               int* __restrict__ hs,
                               int* __restrict__ rs,
                               int* __restrict__ ts, int nE)
{
    int e = blockIdx.x * blockDim.x + threadIdx.x;
    if (e >= nE) return;
    int u = h[e];
    int pos = atomicAdd(&cursor[u], 1);
    hs[pos] = u;
    rs[pos] = r[e];
    ts[pos] = t[e];
}

// ---------------------------------------------------------------------------
// Per-slot score: leaky_relu( (EW1[h] + RW[r] + EW3[t]) . a , 0.2 )
// ---------------------------------------------------------------------------
__global__ void score_kernel(const int* __restrict__ hs,
                             const int* __restrict__ rs,
                             const int* __restrict__ ts,
                             const float* __restrict__ EW1,
                             const float* __restrict__ RW,
                             const float* __restrict__ EW3,
                             const float* __restrict__ a,
                             float* __restrict__ score, int nE)
{
    __shared__ float sa[DD];
    if (threadIdx.x < DD) sa[threadIdx.x] = a[threadIdx.x];
    __syncthreads();
    int e = blockIdx.x * blockDim.x + threadIdx.x;
    if (e >= nE) return;
    const float* p1 = EW1 + hs[e] * DD;
    const float* p2 = RW  + rs[e] * DD;
    const float* p3 = EW3 + ts[e] * DD;
    float acc = 0.f;
    for (int j = 0; j < DD; j++) acc += (p1[j] + p2[j] + p3[j]) * sa[j];
    score[e] = acc >= 0.f ? acc : 0.2f * acc;
}

// ---------------------------------------------------------------------------
// Per-head softmax over contiguous sorted slots (in place score -> alpha)
// ---------------------------------------------------------------------------
__global__ void softmax_kernel(const int* __restrict__ offs, float* __restrict__ score)
{
    int u = blockIdx.x * blockDim.x + threadIdx.x;
    if (u >= N_ENT) return;
    int s0 = offs[u], s1 = offs[u + 1];
    if (s0 >= s1) return;
    float m = -1e30f;
    for (int s = s0; s < s1; s++) m = fmaxf(m, score[s]);
    float sum = 0.f;
    for (int s = s0; s < s1; s++) {
        float ex = __expf(score[s] - m);
        score[s] = ex;
        sum += ex;
    }
    float inv = 1.f / (sum + 1e-9f);
    for (int s = s0; s < s1; s++) score[s] *= inv;
}

// ---------------------------------------------------------------------------
// Per-(head, j) weighted accumulate:
//   out[u][j] = (sum_s alpha_s) * EW1[u][j] + sum_s alpha_s*(RW[r_s][j]+EW3[t_s][j])
//   (+ base[u][j] for the final residual layer)
// ---------------------------------------------------------------------------
__global__ void accum_kernel(const int* __restrict__ offs,
                             const int* __restrict__ rs,
                             const int* __restrict__ ts,
                             const float* __restrict__ alpha,
                             const float* __restrict__ EW1,
                             const float* __restrict__ RW,
                             const float* __restrict__ EW3,
                             const float* __restrict__ base,   // may be null
                             float* __restrict__ outp)
{
    int idx = blockIdx.x * blockDim.x + threadIdx.x;
    if (idx >= N_ENT * DD) return;
    int u = idx / DD, j = idx - u * DD;
    int s0 = offs[u], s1 = offs[u + 1];
    float w1 = EW1[idx];
    float acc = 0.f, asum = 0.f;
    for (int s = s0; s < s1; s++) {
        float al = alpha[s];
        asum += al;
        acc += al * (RW[rs[s] * DD + j] + EW3[ts[s] * DD + j]);
    }
    acc += asum * w1;
    if (base) acc += base[idx];
    outp[idx] = acc;
}

// ---------------------------------------------------------------------------
extern "C" void kernel_launch(void* const* d_in, const int* in_sizes, int n_in,
                              void* d_out, int out_size, void* d_ws, size_t ws_size,
                              hipStream_t stream)
{
    const int*   h   = (const int*)d_in[0];
    const int*   r   = (const int*)d_in[1];
    const int*   t   = (const int*)d_in[2];
    const float* E   = (const float*)d_in[3];
    const float* R   = (const float*)d_in[4];
    const float* W0  = (const float*)d_in[5];
    const float* a0  = (const float*)d_in[6];
    const float* Wr0 = (const float*)d_in[7];
    const float* W1  = (const float*)d_in[8];
    const float* a1  = (const float*)d_in[9];
    const float* Wr1 = (const float*)d_in[10];
    const float* Wd  = (const float*)d_in[11];
    const float* bd  = (const float*)d_in[12];

    float* out_ent = (float*)d_out;                 // [N_ENT, DD]
    float* out_rel = out_ent + (size_t)N_ENT * DD;  // [N_REL, DD]

    // workspace layout (~113.5 MB total, all fp32/int32)
    float* ws_f  = (float*)d_ws;
    float* EW1   = ws_f;                       // 5,000,000
    float* EW3   = EW1 + (size_t)N_ENT * DD;   // 5,000,000
    float* Ed    = EW3 + (size_t)N_ENT * DD;   // 5,000,000
    float* e0    = Ed  + (size_t)N_ENT * DD;   // 5,000,000
    float* RW    = e0  + (size_t)N_ENT * DD;   // 25,000
    float* rel0  = RW  + (size_t)N_REL * DD;   // 25,000
    float* score = rel0 + (size_t)N_REL * DD;  // 2,000,000
    int* counts  = (int*)(score + N_EDGES);    // 100,000
    int* offs    = counts + N_ENT;             // 100,001
    int* cursor  = offs + N_ENT + 1;           // 100,000
    int* hs      = cursor + N_ENT;             // 2,000,000
    int* rs      = hs + N_EDGES;               // 2,000,000
    int* ts      = rs + N_EDGES;               // 2,000,000

    const int BLK = 256;
    const int gE  = (N_EDGES + BLK - 1) / BLK;        // edge-parallel
    const int gU  = (N_ENT + BLK - 1) / BLK;          // head-parallel
    const int gUD = (N_ENT * DD + BLK - 1) / BLK;     // (head, j)-parallel
    const int gRD = (N_REL * DD + BLK - 1) / BLK;

    // ---- CSR build (shared by both layers) ----
    hipMemsetAsync(counts, 0, (size_t)N_ENT * sizeof(int), stream);
    hist_kernel<<<gE, BLK, 0, stream>>>(h, counts, N_EDGES);
    scan_kernel<<<1, 1024, 0, stream>>>(counts, offs, cursor, N_ENT);
    scatter_kernel<<<gE, BLK, 0, stream>>>(h, r, t, cursor, hs, rs, ts, N_EDGES);

    // ---- layer 0 precompute ----
    // rel0 = relu(R @ Wr0), RW = R @ W0[50:100]
    rel_pre_kernel<<<gRD, BLK, 0, stream>>>(R, Wr0, W0 + DD * DD, 1, rel0, RW);
    // EW1 = E @ W0[:50], EW3 = E @ W0[100:150], Ed = E @ Wd + bd
    ent_pre_kernel<<<gUD, BLK, 0, stream>>>(E, N_ENT, W0, W0 + 2 * DD * DD, Wd, bd,
                                            EW1, EW3, Ed);

    // ---- layer 0 attention ----
    score_kernel<<<gE, BLK, 0, stream>>>(hs, rs, ts, EW1, RW, EW3, a0, score, N_EDGES);
    softmax_kernel<<<gU, BLK, 0, stream>>>(offs, score);
    accum_kernel<<<gUD, BLK, 0, stream>>>(offs, rs, ts, score, EW1, RW, EW3,
                                          nullptr, e0);

    // ---- layer 1 precompute ----
    // rel1 = rel0 @ Wr1 (no relu) -> out_rel ; RW = rel0 @ W1[50:100]
    rel_pre_kernel<<<gRD, BLK, 0, stream>>>(rel0, Wr1, W1 + DD * DD, 0, out_rel, RW);
    // EW1 = e0 @ W1[:50], EW3 = e0 @ W1[100:150]
    ent_pre_kernel<<<gUD, BLK, 0, stream>>>(e0, N_ENT, W1, W1 + 2 * DD * DD,
                                            nullptr, nullptr, EW1, EW3, nullptr);

    // ---- layer 1 attention + fused residual (Ed already holds E@Wd + bd) ----
    score_kernel<<<gE, BLK, 0, stream>>>(hs, rs, ts, EW1, RW, EW3, a1, score, N_EDGES);
    softmax_kernel<<<gU, BLK, 0, stream>>>(offs, score);
    accum_kernel<<<gUD, BLK, 0, stream>>>(offs, rs, ts, score, EW1, RW, EW3,
                                          Ed, out_ent);
}